// Round 1
// baseline (900.240 us; speedup 1.0000x reference)
//
#include <hip/hip_runtime.h>
#include <hip/hip_bf16.h>

#define NN 1000000   // NUM_NODES
#define MD 128       // MEM_DIM == MSG_DIM
#define CD 256       // C = MSG_DIM + MEM_DIM
#define BB 262144    // B

typedef __attribute__((ext_vector_type(8))) short bf16x8;
typedef __attribute__((ext_vector_type(4))) float f32x4;

__device__ inline unsigned short f2bf(float f) {
    // round-to-nearest-even f32 -> bf16 (inputs are finite normals)
    unsigned int u = __float_as_uint(f);
    unsigned int r = (u + 0x7FFFu + ((u >> 16) & 1u)) >> 16;
    return (unsigned short)r;
}

__global__ void k_mask_init(unsigned char* __restrict__ mask) {
    int i = blockIdx.x * blockDim.x + threadIdx.x;
    if (i < NN) mask[i] = 0;
}

__global__ void k_mask_set(const int* __restrict__ ids, unsigned char* __restrict__ mask) {
    int b = blockIdx.x * blockDim.x + threadIdx.x;
    if (b < BB) mask[ids[b]] = 1;
}

// Precompute Wp[c][d] = conv_w[c,3] * lin_w[d,c] in bf16, laid out fragment-linear:
// chunk index = (ntile*8 + kstep)*64 + lane, chunk j-th element =
//   Wp[d = ntile*16 + (lane&15)][c = kstep*32 + (lane>>4)*8 + j]
// so the update kernel's ds_read_b128 per (tile,kstep) is lane-contiguous (no bank conflicts).
__global__ void k_wp(const float* __restrict__ conv_w, const float* __restrict__ lin_w,
                     unsigned short* __restrict__ wp) {
    int idx = blockIdx.x * blockDim.x + threadIdx.x;
    if (idx >= 4096) return;
    int lane = idx & 63;
    int chunk = idx >> 6;
    int nt = chunk >> 3;
    int ks = chunk & 7;
    int d  = nt * 16 + (lane & 15);
    int c0 = ks * 32 + (lane >> 4) * 8;
    bf16x8 v;
    #pragma unroll
    for (int j = 0; j < 8; ++j) {
        int c = c0 + j;
        v[j] = (short)f2bf(lin_w[d * CD + c] * conv_w[c * 7 + 3]);
    }
    ((bf16x8*)wp)[idx] = v;
}

// Update kernel: 64 rows/block, 256 threads = 4 waves x 16 rows.
// Per wave: 8 n-tiles (d=0..127) x 8 k-steps (c=0..255) of mfma_f32_16x16x32_bf16.
__launch_bounds__(256, 2)
__global__ void k_update(const int* __restrict__ ids,
                         const float* __restrict__ msgs,
                         const float* __restrict__ mem,
                         const unsigned short* __restrict__ wp,
                         const float* __restrict__ lin_b,
                         const float* __restrict__ gamma,
                         const float* __restrict__ beta,
                         float* __restrict__ out) {
    __shared__ bf16x8 sWp[4096];   // 64 KB; reused as 64x132 f32 out-stage after compute

    int tid = threadIdx.x;
    const bf16x8* gwp = (const bf16x8*)wp;
    #pragma unroll
    for (int i = 0; i < 16; ++i) sWp[tid + i * 256] = gwp[tid + i * 256];

    int lane = tid & 63;
    int wave = tid >> 6;
    int m    = lane & 15;        // A-operand row within wave tile
    int quad = lane >> 4;        // 0..3
    int rowBase = blockIdx.x * 64 + wave * 16;
    int b   = rowBase + m;
    int nid = ids[b];

    f32x4 acc[8];
    #pragma unroll
    for (int t = 0; t < 8; ++t) acc[t] = (f32x4){0.f, 0.f, 0.f, 0.f};

    __syncthreads();

    #pragma unroll
    for (int ks = 0; ks < 8; ++ks) {
        int c0 = ks * 32 + quad * 8;   // A k-range: quad*8 + j
        const float* src = (ks < 4) ? (msgs + (size_t)b * MD + c0)
                                    : (mem + (size_t)nid * MD + (c0 - 128));
        float4 f0 = ((const float4*)src)[0];
        float4 f1 = ((const float4*)src)[1];
        bf16x8 a;
        a[0] = (short)f2bf(f0.x); a[1] = (short)f2bf(f0.y);
        a[2] = (short)f2bf(f0.z); a[3] = (short)f2bf(f0.w);
        a[4] = (short)f2bf(f1.x); a[5] = (short)f2bf(f1.y);
        a[6] = (short)f2bf(f1.z); a[7] = (short)f2bf(f1.w);
        #pragma unroll
        for (int t = 0; t < 8; ++t) {
            bf16x8 bb = sWp[(t * 8 + ks) * 64 + lane];
            acc[t] = __builtin_amdgcn_mfma_f32_16x16x32_bf16(a, bb, acc[t], 0, 0, 0);
        }
    }

    // Epilogue: +bias, LayerNorm per row. C/D layout: row = quad*4 + reg, col = t*16 + m.
    float vals[8][4];
    float sum[4] = {0, 0, 0, 0}, ssq[4] = {0, 0, 0, 0};
    float gg[8], bt[8];
    #pragma unroll
    for (int t = 0; t < 8; ++t) {
        int d = t * 16 + m;
        float bias = lin_b[d];
        gg[t] = gamma[d];
        bt[t] = beta[d];
        #pragma unroll
        for (int r = 0; r < 4; ++r) {
            float v = acc[t][r] + bias;
            vals[t][r] = v;
            sum[r] += v;
            ssq[r] += v * v;
        }
    }
    // reduce across the 16 lanes holding each row (lane>>4 fixed per row-group)
    #pragma unroll
    for (int off = 1; off < 16; off <<= 1) {
        #pragma unroll
        for (int r = 0; r < 4; ++r) {
            sum[r] += __shfl_xor(sum[r], off, 64);
            ssq[r] += __shfl_xor(ssq[r], off, 64);
        }
    }
    float mu[4], rs[4];
    #pragma unroll
    for (int r = 0; r < 4; ++r) {
        mu[r] = sum[r] * (1.0f / 128.0f);
        float var = ssq[r] * (1.0f / 128.0f) - mu[r] * mu[r];
        rs[r] = rsqrtf(var + 1e-5f);
    }

    __syncthreads();               // all waves done reading sWp; reuse as out-stage
    float* sOut = (float*)sWp;     // [64][132] padded (132%32==4 -> 2-way on write, free)
    #pragma unroll
    for (int t = 0; t < 8; ++t) {
        int d = t * 16 + m;
        #pragma unroll
        for (int r = 0; r < 4; ++r) {
            int row = wave * 16 + quad * 4 + r;
            sOut[row * 132 + d] = (vals[t][r] - mu[r]) * rs[r] * gg[t] + bt[t];
        }
    }
    __syncthreads();

    // coalesced scatter: one float4 per thread-iter, 512B contiguous per row
    #pragma unroll
    for (int i = 0; i < 8; ++i) {
        int idx = tid + i * 256;         // 0..2047 = 64 rows * 32 float4
        int row = idx >> 5;
        int c4  = (idx & 31) * 4;
        int orow = ids[blockIdx.x * 64 + row];
        float4 v = *(float4*)&sOut[row * 132 + c4];
        *(float4*)&out[(size_t)orow * MD + c4] = v;
    }
}

// Copy all rows NOT updated (mask==0): saves re-writing the 128MB of updated rows.
__global__ void k_merge(const unsigned char* __restrict__ mask,
                        const float* __restrict__ mem,
                        float* __restrict__ out) {
    long long idx = (long long)blockIdx.x * blockDim.x + threadIdx.x;
    if (idx >= (long long)NN * 32) return;
    int n = (int)(idx >> 5);
    int c = ((int)idx & 31) * 4;
    if (!mask[n]) {
        float4 v = *(const float4*)&mem[(size_t)n * MD + c];
        *(float4*)&out[(size_t)n * MD + c] = v;
    }
}

extern "C" void kernel_launch(void* const* d_in, const int* in_sizes, int n_in,
                              void* d_out, int out_size, void* d_ws, size_t ws_size,
                              hipStream_t stream) {
    const int*   ids    = (const int*)d_in[0];
    const float* msgs   = (const float*)d_in[1];
    const float* mem    = (const float*)d_in[2];
    const float* conv_w = (const float*)d_in[3];
    const float* lin_w  = (const float*)d_in[4];
    const float* lin_b  = (const float*)d_in[5];
    const float* gamma  = (const float*)d_in[6];
    const float* beta   = (const float*)d_in[7];
    float* out = (float*)d_out;

    unsigned char*  mask = (unsigned char*)d_ws;
    unsigned short* wp   = (unsigned short*)((char*)d_ws + (1 << 20));

    k_mask_init<<<(NN + 255) / 256, 256, 0, stream>>>(mask);
    k_mask_set<<<(BB + 255) / 256, 256, 0, stream>>>(ids, mask);
    k_wp<<<16, 256, 0, stream>>>(conv_w, lin_w, wp);
    k_update<<<BB / 64, 256, 0, stream>>>(ids, msgs, mem, wp, lin_b, gamma, beta, out);
    k_merge<<<(int)(((long long)NN * 32 + 255) / 256), 256, 0, stream>>>(mask, mem, out);
}